// Round 15
// baseline (113.904 us; speedup 1.0000x reference)
//
#include <hip/hip_runtime.h>
#include <math.h>

#define D 512
#define OWN 128     // owned rows per fused block (R13/R14-proven geometry)
#define HALOA 8     // halo rows each side; supports k <= 8 (bench k = 4)
#define NFIN 32     // blocks participating in fused finalization

__device__ __forceinline__ float dot4(float4 a, float4 b) {
    return a.x*b.x + a.y*b.y + a.z*b.z + a.w*b.w;
}

// ---- K-ALL: R14's k_ab phases 1-4 verbatim + last-32-blocks finalization ---
__global__ __launch_bounds__(256) void k_all(
    const float* __restrict__ f, const float* __restrict__ w,
    const float* __restrict__ bptr, const int* __restrict__ kptr,
    float* __restrict__ e_out, float* __restrict__ psum,
    float* __restrict__ partial, float* __restrict__ bag,
    float* __restrict__ w_out, int* cnt, int n, int nbA)
{
    __shared__ float dots[OWN + 2 * HALOA];   // 144
    __shared__ float e_sh[OWN + 2 * HALOA];   // 144
    __shared__ float uu_sh[OWN];              // 128
    __shared__ float sm[4];
    __shared__ float ginv;
    __shared__ int   s_old;
    __shared__ float sred[256];
    int lane = threadIdx.x & 63;
    int wid  = threadIdx.x >> 6;
    int t    = threadIdx.x;
    int g0   = blockIdx.x * OWN - HALOA;      // global row of local index 0

    const float4* wr = (const float4*)w;
    float4 b0 = wr[lane], b1 = wr[lane + 64];

    // phase 1: dots (wave `wid` handles local rows wid, wid+4, ...) [R14]
    for (int lr = wid; lr < OWN + 2 * HALOA; lr += 4) {
        int row = g0 + lr;
        bool v = (row >= 0) && (row < n);
        const float4* fr = (const float4*)(f + (size_t)(v ? row : 0) * D);
        float4 a0 = fr[lane], a1 = fr[lane + 64];
        float s = dot4(a0, b0) + dot4(a1, b1);
        #pragma unroll
        for (int off = 32; off; off >>= 1) s += __shfl_down(s, off);
        if (lane == 0) dots[lr] = v ? s : 0.f;
    }
    __syncthreads();

    int k = *kptr;
    float bias = bptr[0];

    // phase 2: e for local rows any owned window touches [R14]
    float e_reg = 0.f;
    if (t < OWN + 2 * HALOA) {
        int i = g0 + t;
        if (t >= HALOA - k && t < HALOA + OWN + k && i >= 0 && i < n) {
            int lo = max(i - k, 0), hi = min(i + k, n - 1);
            float s = 0.f;
            for (int q = lo; q <= hi; ++q) s += dots[q - g0];
            e_reg = __expf(s / (float)(hi - lo + 1) + bias);
        }
        e_sh[t] = e_reg;
    }
    __syncthreads();

    // psum over owned rows [R14]
    float pv = (t >= HALOA && t < HALOA + OWN) ? e_reg : 0.f;
    #pragma unroll
    for (int off = 32; off; off >>= 1) pv += __shfl_down(pv, off);
    if (lane == 0) sm[wid] = pv;
    __syncthreads();
    if (t == 0) psum[blockIdx.x] = sm[0] + sm[1] + sm[2] + sm[3];

    // phase 3: uu (LDS only) + e_out [R14]
    if (t < OWN) {
        int j = blockIdx.x * OWN + t;
        float acc = 0.f;
        if (j < n) {
            e_out[j] = e_sh[t + HALOA];
            int lo = max(j - k, 0), hi = min(j + k, n - 1);
            for (int i = lo; i <= hi; ++i) {
                int li = max(i - k, 0), hh = min(i + k, n - 1);
                acc += e_sh[i - g0] * __builtin_amdgcn_rcpf((float)(hh - li + 1));
            }
        }
        uu_sh[t] = acc;
    }
    __syncthreads();

    // phase 4: partial bag (R9-proven loop; threads 0-127; uu from LDS) [R14]
    if (t < 128) {
        int j0 = blockIdx.x * OWN;
        int j1 = min(j0 + OWN, n);
        float4 acc0 = make_float4(0.f,0.f,0.f,0.f);
        float4 acc1 = make_float4(0.f,0.f,0.f,0.f);
        float4 acc2 = make_float4(0.f,0.f,0.f,0.f);
        float4 acc3 = make_float4(0.f,0.f,0.f,0.f);
        int j = j0;
        for (; j + 4 <= j1; j += 4) {
            int lr = j - j0;
            float u0 = uu_sh[lr], u1 = uu_sh[lr+1], u2 = uu_sh[lr+2], u3 = uu_sh[lr+3];
            float4 v0 = ((const float4*)(f + (size_t)(j  ) * D))[t];
            float4 v1 = ((const float4*)(f + (size_t)(j+1) * D))[t];
            float4 v2 = ((const float4*)(f + (size_t)(j+2) * D))[t];
            float4 v3 = ((const float4*)(f + (size_t)(j+3) * D))[t];
            acc0.x += u0*v0.x; acc0.y += u0*v0.y; acc0.z += u0*v0.z; acc0.w += u0*v0.w;
            acc1.x += u1*v1.x; acc1.y += u1*v1.y; acc1.z += u1*v1.z; acc1.w += u1*v1.w;
            acc2.x += u2*v2.x; acc2.y += u2*v2.y; acc2.z += u2*v2.z; acc2.w += u2*v2.w;
            acc3.x += u3*v3.x; acc3.y += u3*v3.y; acc3.z += u3*v3.z; acc3.w += u3*v3.w;
        }
        for (; j < j1; ++j) {
            float uj = uu_sh[j - j0];
            float4 v = ((const float4*)(f + (size_t)j * D))[t];
            acc0.x += uj*v.x; acc0.y += uj*v.y; acc0.z += uj*v.z; acc0.w += uj*v.w;
        }
        float4 a;
        a.x = (acc0.x + acc1.x) + (acc2.x + acc3.x);
        a.y = (acc0.y + acc1.y) + (acc2.y + acc3.y);
        a.z = (acc0.z + acc1.z) + (acc2.z + acc3.z);
        a.w = (acc0.w + acc1.w) + (acc2.w + acc3.w);
        ((float4*)(partial + (size_t)blockIdx.x * D))[t] = a;
    }

    // ---- completion protocol: release own writes, count, last 32 finalize --
    __syncthreads();
    if (t == 0) {
        __threadfence();                       // release partial/psum/e_out
        s_old = atomicAdd(cnt, 1);
    }
    __syncthreads();
    int old = s_old;
    if (old < nbA - NFIN) return;
    int li = old - (nbA - NFIN);               // finalization slice 0..31

    if (t == 0) {
        while (__hip_atomic_load(cnt, __ATOMIC_ACQUIRE, __HIP_MEMORY_SCOPE_AGENT) < nbA)
            __builtin_amdgcn_s_sleep(2);
        __threadfence();                       // acquire all blocks' writes
    }
    __syncthreads();

    // (a) inv = 1/sum(psum)  — redundant per participant, bitwise identical
    float s = 0.f;
    for (int idx = t; idx < nbA; idx += 256) s += psum[idx];
    #pragma unroll
    for (int off = 32; off; off >>= 1) s += __shfl_down(s, off);
    if (lane == 0) sm[wid] = s;
    __syncthreads();
    if (t == 0) ginv = 1.f / (sm[0] + sm[1] + sm[2] + sm[3]);
    __syncthreads();
    float inv = ginv;

    // (b) bag columns [li*16, li*16+16)  (k_rbag pattern within one block)
    {
        int c = li * 16 + (t & 15);
        int r = t >> 4;
        float acc = 0.f;
        for (int b = r; b < nbA; b += 16) acc += partial[(size_t)b * D + c];
        sred[t] = acc;
        __syncthreads();
        if (t < 16) {
            float tt = 0.f;
            #pragma unroll
            for (int q = 0; q < 16; ++q) tt += sred[q * 16 + t];
            bag[li * 16 + t] = tt * inv;
        }
    }

    // (c) w_out slice
    int per = (n + NFIN - 1) / NFIN;
    int jend = min(li * per + per, n);
    for (int j = li * per + t; j < jend; j += 256)
        w_out[j] = e_out[j] * inv;
}

extern "C" void kernel_launch(void* const* d_in, const int* in_sizes, int n_in,
                              void* d_out, int out_size, void* d_ws, size_t ws_size,
                              hipStream_t stream) {
    const float* f  = (const float*)d_in[0];
    const float* aw = (const float*)d_in[1];
    const float* ab = (const float*)d_in[2];
    const int*   kp = (const int*)d_in[3];
    int n = in_sizes[0] / D;

    float* bag   = (float*)d_out;        // [512]
    float* w_out = (float*)d_out + D;    // [n]

    int nbA = (n + OWN - 1) / OWN;       // 782 fused blocks

    int*   cnt     = (int*)d_ws;                 // [0..15] counter line
    float* wsf     = (float*)d_ws;
    float* e       = wsf + 16;                   // n
    float* psum    = e + n;                      // nbA
    size_t poff    = ((16 + (size_t)n + (size_t)nbA) + 31) & ~(size_t)31;
    float* partial = wsf + poff;                 // nbA * D

    hipMemsetAsync(cnt, 0, 64, stream);          // zero counter each launch
    k_all<<<nbA, 256, 0, stream>>>(f, aw, ab, kp, e, psum, partial,
                                   bag, w_out, cnt, n, nbA);
}

// Round 16
// 86.825 us; speedup vs baseline: 1.3119x; 1.3119x over previous
//
#include <hip/hip_runtime.h>
#include <math.h>

#define D 512
#define OWN 128     // owned rows per fused block (R13/R14-proven geometry)
#define HALOA 8     // halo rows each side; supports k <= 8 (bench k = 4)

__device__ __forceinline__ float dot4(float4 a, float4 b) {
    return a.x*b.x + a.y*b.y + a.z*b.z + a.w*b.w;
}

// ---- K-AB: fused dot + e + uu (LDS-local) + partial-bag --------------------
// R14-proven structure. R16 change: phase 1 processes 4 independent rows per
// wave-iteration (ILP-4: 8 loads + 4 shuffle chains in flight) instead of 1.
__global__ __launch_bounds__(256) void k_ab(
    const float* __restrict__ f, const float* __restrict__ w,
    const float* __restrict__ bptr, const int* __restrict__ kptr,
    float* __restrict__ e_out, float* __restrict__ psum,
    float* __restrict__ partial, int n)
{
    __shared__ float dots[OWN + 2 * HALOA];   // 144
    __shared__ float e_sh[OWN + 2 * HALOA];   // 144
    __shared__ float uu_sh[OWN];              // 128
    __shared__ float sm[4];
    int lane = threadIdx.x & 63;
    int wid  = threadIdx.x >> 6;
    int t    = threadIdx.x;
    int g0   = blockIdx.x * OWN - HALOA;      // global row of local index 0

    const float4* wr = (const float4*)w;
    float4 b0 = wr[lane], b1 = wr[lane + 64];

    // phase 1 (ILP-4): 144 rows = 36 groups of 4; wave `wid` takes groups
    // wid, wid+4, ... (9 iterations, 4 independent rows each).
    const int NLOC = OWN + 2 * HALOA;         // 144
    for (int grp = wid; grp < NLOC / 4; grp += 4) {
        int lr = grp * 4;
        int r0 = g0 + lr;
        bool v0 = (r0 >= 0)     && (r0 < n);
        bool v1 = (r0 + 1 >= 0) && (r0 + 1 < n);
        bool v2 = (r0 + 2 >= 0) && (r0 + 2 < n);
        bool v3 = (r0 + 3 >= 0) && (r0 + 3 < n);
        const float4* p0 = (const float4*)(f + (size_t)(v0 ? r0     : 0) * D);
        const float4* p1 = (const float4*)(f + (size_t)(v1 ? r0 + 1 : 0) * D);
        const float4* p2 = (const float4*)(f + (size_t)(v2 ? r0 + 2 : 0) * D);
        const float4* p3 = (const float4*)(f + (size_t)(v3 ? r0 + 3 : 0) * D);
        float4 x0a = p0[lane], x0b = p0[lane + 64];
        float4 x1a = p1[lane], x1b = p1[lane + 64];
        float4 x2a = p2[lane], x2b = p2[lane + 64];
        float4 x3a = p3[lane], x3b = p3[lane + 64];
        float s0 = dot4(x0a, b0) + dot4(x0b, b1);
        float s1 = dot4(x1a, b0) + dot4(x1b, b1);
        float s2 = dot4(x2a, b0) + dot4(x2b, b1);
        float s3 = dot4(x3a, b0) + dot4(x3b, b1);
        #pragma unroll
        for (int off = 32; off; off >>= 1) {
            s0 += __shfl_down(s0, off);
            s1 += __shfl_down(s1, off);
            s2 += __shfl_down(s2, off);
            s3 += __shfl_down(s3, off);
        }
        if (lane == 0) {
            dots[lr]     = v0 ? s0 : 0.f;
            dots[lr + 1] = v1 ? s1 : 0.f;
            dots[lr + 2] = v2 ? s2 : 0.f;
            dots[lr + 3] = v3 ? s3 : 0.f;
        }
    }
    __syncthreads();

    int k = *kptr;
    float bias = bptr[0];

    // phase 2: e for local rows any owned window touches [R14]
    float e_reg = 0.f;
    if (t < NLOC) {
        int i = g0 + t;
        if (t >= HALOA - k && t < HALOA + OWN + k && i >= 0 && i < n) {
            int lo = max(i - k, 0), hi = min(i + k, n - 1);
            float s = 0.f;
            for (int q = lo; q <= hi; ++q) s += dots[q - g0];
            e_reg = __expf(s / (float)(hi - lo + 1) + bias);
        }
        e_sh[t] = e_reg;
    }
    __syncthreads();

    // psum over owned rows [R14]
    float pv = (t >= HALOA && t < HALOA + OWN) ? e_reg : 0.f;
    #pragma unroll
    for (int off = 32; off; off >>= 1) pv += __shfl_down(pv, off);
    if (lane == 0) sm[wid] = pv;
    __syncthreads();
    if (t == 0) psum[blockIdx.x] = sm[0] + sm[1] + sm[2] + sm[3];

    // phase 3: uu (LDS only) + e_out [R14]
    if (t < OWN) {
        int j = blockIdx.x * OWN + t;
        float acc = 0.f;
        if (j < n) {
            e_out[j] = e_sh[t + HALOA];
            int lo = max(j - k, 0), hi = min(j + k, n - 1);
            for (int i = lo; i <= hi; ++i) {
                int li = max(i - k, 0), hh = min(i + k, n - 1);
                acc += e_sh[i - g0] * __builtin_amdgcn_rcpf((float)(hh - li + 1));
            }
        }
        uu_sh[t] = acc;
    }
    __syncthreads();

    // phase 4: partial bag (R9-proven loop; threads 0-127; uu from LDS) [R14]
    if (t < 128) {
        int j0 = blockIdx.x * OWN;
        int j1 = min(j0 + OWN, n);
        float4 acc0 = make_float4(0.f,0.f,0.f,0.f);
        float4 acc1 = make_float4(0.f,0.f,0.f,0.f);
        float4 acc2 = make_float4(0.f,0.f,0.f,0.f);
        float4 acc3 = make_float4(0.f,0.f,0.f,0.f);
        int j = j0;
        for (; j + 4 <= j1; j += 4) {
            int lr = j - j0;
            float u0 = uu_sh[lr], u1 = uu_sh[lr+1], u2 = uu_sh[lr+2], u3 = uu_sh[lr+3];
            float4 v0 = ((const float4*)(f + (size_t)(j  ) * D))[t];
            float4 v1 = ((const float4*)(f + (size_t)(j+1) * D))[t];
            float4 v2 = ((const float4*)(f + (size_t)(j+2) * D))[t];
            float4 v3 = ((const float4*)(f + (size_t)(j+3) * D))[t];
            acc0.x += u0*v0.x; acc0.y += u0*v0.y; acc0.z += u0*v0.z; acc0.w += u0*v0.w;
            acc1.x += u1*v1.x; acc1.y += u1*v1.y; acc1.z += u1*v1.z; acc1.w += u1*v1.w;
            acc2.x += u2*v2.x; acc2.y += u2*v2.y; acc2.z += u2*v2.z; acc2.w += u2*v2.w;
            acc3.x += u3*v3.x; acc3.y += u3*v3.y; acc3.z += u3*v3.z; acc3.w += u3*v3.w;
        }
        for (; j < j1; ++j) {
            float uj = uu_sh[j - j0];
            float4 v = ((const float4*)(f + (size_t)j * D))[t];
            acc0.x += uj*v.x; acc0.y += uj*v.y; acc0.z += uj*v.z; acc0.w += uj*v.w;
        }
        float4 a;
        a.x = (acc0.x + acc1.x) + (acc2.x + acc3.x);
        a.y = (acc0.y + acc1.y) + (acc2.y + acc3.y);
        a.z = (acc0.z + acc1.z) + (acc2.z + acc3.z);
        a.w = (acc0.w + acc1.w) + (acc2.w + acc3.w);
        ((float4*)(partial + (size_t)blockIdx.x * D))[t] = a;
    }
}

// ---- K-final (R13/R14-proven): S from psum, bag = reduce*inv, w = e*inv ----
__global__ void k_final(const float* __restrict__ partial, const float* __restrict__ psum,
                        int nbp, int nbs, const float* __restrict__ e,
                        float* __restrict__ bag, float* __restrict__ w_out, int n) {
    __shared__ float sm[4];
    __shared__ float ginv;
    int lane = threadIdx.x & 63, wid = threadIdx.x >> 6;

    float s = 0.f;
    for (int idx = threadIdx.x; idx < nbs; idx += 256) s += psum[idx];
    #pragma unroll
    for (int off = 32; off; off >>= 1) s += __shfl_down(s, off);
    if (lane == 0) sm[wid] = s;
    __syncthreads();
    if (threadIdx.x == 0)
        ginv = 1.f / (sm[0] + sm[1] + sm[2] + sm[3]);
    __syncthreads();
    float inv = ginv;

    if (blockIdx.x < 32) {
        int c = blockIdx.x * 16 + (threadIdx.x & 15);
        int r = threadIdx.x >> 4;
        float acc = 0.f;
        for (int b = r; b < nbp; b += 16) acc += partial[(size_t)b * D + c];
        __shared__ float sred[256];
        sred[threadIdx.x] = acc;
        __syncthreads();
        if (threadIdx.x < 16) {
            float tt = 0.f;
            #pragma unroll
            for (int q = 0; q < 16; ++q) tt += sred[q * 16 + threadIdx.x];
            bag[blockIdx.x * 16 + threadIdx.x] = tt * inv;
        }
    }

    for (int j = blockIdx.x * 256 + threadIdx.x; j < n; j += gridDim.x * 256)
        w_out[j] = e[j] * inv;
}

extern "C" void kernel_launch(void* const* d_in, const int* in_sizes, int n_in,
                              void* d_out, int out_size, void* d_ws, size_t ws_size,
                              hipStream_t stream) {
    const float* f  = (const float*)d_in[0];
    const float* aw = (const float*)d_in[1];
    const float* ab = (const float*)d_in[2];
    const int*   kp = (const int*)d_in[3];
    int n = in_sizes[0] / D;

    float* bag   = (float*)d_out;        // [512]
    float* w_out = (float*)d_out + D;    // [n]

    int nbA = (n + OWN - 1) / OWN;       // 782 fused blocks
    int nb2 = (n + 255) / 256;           // 391 final blocks

    float* wsf     = (float*)d_ws;
    float* e       = wsf;                        // n
    float* psum    = wsf + n;                    // nbA
    size_t poff    = (((size_t)n + (size_t)nbA) + 31) & ~(size_t)31;
    float* partial = wsf + poff;                 // nbA * D

    k_ab   <<<nbA, 256, 0, stream>>>(f, aw, ab, kp, e, psum, partial, n);
    k_final<<<nb2, 256, 0, stream>>>(partial, psum, nbA, nbA, e, bag, w_out, n);
}